// Round 1
// baseline (327.789 us; speedup 1.0000x reference)
//
#include <hip/hip_runtime.h>
#include <hip/hip_fp8.h>
#include <math.h>

#define NN 3072
#define NU 1024
#define NI 2048
#define DD 128
#define BB 8192
#define GAMMA_F 0.2f

#define SCALE_A 524288.0f                // 2^19
#define F8SCALE2 1.9073486328125e-06f    // 2^-19  (C*2^38 -> A2*2^19 for fp8)
#define DESCALE38 3.637978807091713e-12f // 2^-38  (C -> true A^k values)

// packed fp8 layout: [k/64][row][k%64]; one k-block = NN rows x 64 B
#define KBLK ((size_t)NN * 64)

typedef __attribute__((ext_vector_type(4))) float f32x4;
typedef __attribute__((ext_vector_type(16))) float f32x16;
typedef __attribute__((ext_vector_type(4))) int i32x4;
typedef __attribute__((ext_vector_type(8))) int i32x8;

static __device__ inline unsigned short bf16bits(float x) {
  union { unsigned u; float f; } cv;
  cv.f = x;
  unsigned r = cv.u + 0x7fff + ((cv.u >> 16) & 1);  // RNE
  return (unsigned short)(r >> 16);
}

// pack 4 floats -> 4 fp8 e4m3 (OCP) bytes
static __device__ inline unsigned pk4_f8(float a, float b, float c, float d) {
#if defined(__has_builtin)
#if __has_builtin(__builtin_amdgcn_cvt_pk_fp8_f32)
  int p = __builtin_amdgcn_cvt_pk_fp8_f32(a, b, 0, false);
  p = __builtin_amdgcn_cvt_pk_fp8_f32(c, d, p, true);
  return (unsigned)p;
#else
  return (unsigned)__hip_fp8_e4m3(a).__x | ((unsigned)__hip_fp8_e4m3(b).__x << 8) |
         ((unsigned)__hip_fp8_e4m3(c).__x << 16) |
         ((unsigned)__hip_fp8_e4m3(d).__x << 24);
#endif
#else
  return (unsigned)__hip_fp8_e4m3(a).__x | ((unsigned)__hip_fp8_e4m3(b).__x << 8) |
         ((unsigned)__hip_fp8_e4m3(c).__x << 16) |
         ((unsigned)__hip_fp8_e4m3(d).__x << 24);
#endif
}

static __device__ inline void atomAddF(float* p, float v) {
#if defined(__has_builtin)
#if __has_builtin(__builtin_amdgcn_global_atomic_fadd_f32)
  __builtin_amdgcn_global_atomic_fadd_f32(
      (__attribute__((address_space(1))) float*)p, v);
#else
  unsafeAtomicAdd(p, v);
#endif
#else
  unsafeAtomicAdd(p, v);
#endif
}

static __device__ inline float block_sum(float s, float* red4) {
  int tid = threadIdx.x;
  for (int off = 32; off; off >>= 1) s += __shfl_down(s, off, 64);
  if ((tid & 63) == 0) red4[tid >> 6] = s;
  __syncthreads();
  return red4[0] + red4[1] + red4[2] + red4[3];
}

static __device__ inline float row_dot_f32(const float* __restrict__ a,
                                           const float* __restrict__ b,
                                           float* red4) {
  const float4* ap = (const float4*)a;
  const float4* bp = (const float4*)b;
  float s = 0.f;
  for (int j = threadIdx.x; j < NN / 4; j += 256) {
    float4 x = ap[j], y = bp[j];
    s += x.x * y.x + x.y * y.y + x.z * y.z + x.w * y.w;
  }
  return block_sum(s, red4);
}

// ---------------------------------------------------------------------------
// topk loaders: fill f[48] with this row's values (one wave, 48 vals/lane).
static __device__ inline void load48_bf(const unsigned short* __restrict__ b0,
                                        int parts, int row, int lane,
                                        float* f) {
  const uint4* r0 = (const uint4*)(b0 + (size_t)row * NN);
#pragma unroll
  for (int j = 0; j < 6; ++j) {
    uint4 q = r0[lane + j * 64];
    unsigned uu[4] = {q.x, q.y, q.z, q.w};
#pragma unroll
    for (int e = 0; e < 4; ++e) {
      f[j * 8 + e * 2] = __uint_as_float(uu[e] << 16);
      f[j * 8 + e * 2 + 1] = __uint_as_float(uu[e] & 0xffff0000u);
    }
  }
  for (int p = 1; p < parts; ++p) {
    const uint4* rp = (const uint4*)(b0 + (size_t)p * NN * NN + (size_t)row * NN);
#pragma unroll
    for (int j = 0; j < 6; ++j) {
      uint4 q = rp[lane + j * 64];
      unsigned uu[4] = {q.x, q.y, q.z, q.w};
#pragma unroll
      for (int e = 0; e < 4; ++e) {
        f[j * 8 + e * 2] += __uint_as_float(uu[e] << 16);
        f[j * 8 + e * 2 + 1] += __uint_as_float(uu[e] & 0xffff0000u);
      }
    }
  }
}

static __device__ inline void load48_f32(const float* __restrict__ A, int row,
                                         int lane, float* f) {
  const float4* r0 = (const float4*)(A + (size_t)row * NN);
#pragma unroll
  for (int j = 0; j < 12; ++j) {
    float4 a = r0[lane + j * 64];
    f[j * 4 + 0] = a.x; f[j * 4 + 1] = a.y;
    f[j * 4 + 2] = a.z; f[j * 4 + 3] = a.w;
  }
}

// ---------------------------------------------------------------------------
// select top-64 of the wave's 64x48 values. Radix on bits [30..16] resolved
// TWO bits per step (counts are monotone c3<=c2<=c1, so "largest 2-bit
// pattern with count>=64" == two greedy single-bit steps) with butterfly
// shfl_xor reduces (all lanes end with the total -> no broadcast). Compact
// (idx*DD, val*descale) into out arrays (128 slots; LDS or global).
static __device__ void select_compact(const float* f, int lane, float descale,
                                      int bf, int* __restrict__ outCnt,
                                      int* __restrict__ outIdx,
                                      float* __restrict__ outVal) {
  unsigned bor = 0, band = 0xffffffffu;
#pragma unroll
  for (int r = 0; r < 48; ++r) {
    unsigned k = __float_as_uint(f[r]);
    bor |= k; band &= k;
  }
  for (int off = 32; off; off >>= 1) {
    bor |= (unsigned)__shfl_xor((int)bor, off, 64);
    band &= (unsigned)__shfl_xor((int)band, off, 64);
  }
  unsigned diff = bor ^ band;
  int hi = diff ? (31 - __clz(diff)) : 16;
  if (hi < 16) hi = 16;
  if (hi > 30) hi = 30;
  unsigned t = band & ~((2u << hi) - 1u);

  int b = hi;
  while (b >= 17) {
    unsigned base = 1u << (b - 1);
    unsigned cand1 = t | base;
    unsigned cand2 = t | (base << 1);
    unsigned cand3 = cand2 | base;
    int c1 = 0, c2 = 0, c3 = 0;
#pragma unroll
    for (int r = 0; r < 48; ++r) {
      unsigned k = __float_as_uint(f[r]);
      c1 += (k >= cand1) ? 1 : 0;
      c2 += (k >= cand2) ? 1 : 0;
      c3 += (k >= cand3) ? 1 : 0;
    }
    for (int off = 32; off; off >>= 1) {
      c1 += __shfl_xor(c1, off, 64);
      c2 += __shfl_xor(c2, off, 64);
      c3 += __shfl_xor(c3, off, 64);
    }
    if (c3 >= 64) t = cand3;
    else if (c2 >= 64) t = cand2;
    else if (c1 >= 64) t = cand1;
    b -= 2;
  }
  if (b == 16) {
    unsigned cand = t | (1u << 16);
    int c = 0;
#pragma unroll
    for (int r = 0; r < 48; ++r) c += (__float_as_uint(f[r]) >= cand) ? 1 : 0;
    for (int off = 32; off; off >>= 1) c += __shfl_xor(c, off, 64);
    if (c >= 64) t = cand;
  }

  int basec = 0;
#pragma unroll
  for (int r = 0; r < 48; ++r) {
    bool keep = __float_as_uint(f[r]) >= t;
    unsigned long long m = __ballot(keep);
    if (keep) {
      int pos = basec + __popcll(m & ((1ull << lane) - 1ull));
      if (pos < 128) {
        int col = bf ? ((r >> 3) * 512 + lane * 8 + (r & 7))
                     : ((r >> 2) * 256 + lane * 4 + (r & 3));
        outIdx[pos] = col << 7;  // pre-scaled by DD for gather addressing
        outVal[pos] = f[r] * descale;
      }
    }
    basec += __popcll(m);
  }
  if (lane == 0) *outCnt = basec < 128 ? basec : 128;
}

// ---------------------------------------------------------------------------
// prep: A -> fp8 PACKED (straight + transposed, x2^19) + fused y1/s1 matvec
// partials. grid 2304 (48x48 tiles of 64x64).
__global__ __launch_bounds__(256) void prep(
    const float* __restrict__ A, const float* __restrict__ vu,
    const float* __restrict__ vv, unsigned char* __restrict__ Af8,
    unsigned char* __restrict__ Atf8, float* __restrict__ y1,
    float* __restrict__ s1) {
  __shared__ float sh[64 * 65 + 512];
  const int bid = blockIdx.x;
  const int t = threadIdx.x;
  const int bx = (bid % 48) * 64, by = (bid / 48) * 64;
  const int rr = t >> 4;
  const int c4 = (t & 15) * 4;
  for (int it = 0; it < 4; ++it) {
    int r = rr + it * 16;
    float4 val = *(const float4*)(A + (size_t)(by + r) * NN + bx + c4);
    sh[r * 65 + c4] = val.x; sh[r * 65 + c4 + 1] = val.y;
    sh[r * 65 + c4 + 2] = val.z; sh[r * 65 + c4 + 3] = val.w;
  }
  __syncthreads();
  {
    int row = t >> 2, ch = t & 3;
    const float* sp = &sh[row * 65 + ch * 16];
    uint4 w;
    w.x = pk4_f8(sp[0] * SCALE_A, sp[1] * SCALE_A, sp[2] * SCALE_A,
                 sp[3] * SCALE_A);
    w.y = pk4_f8(sp[4] * SCALE_A, sp[5] * SCALE_A, sp[6] * SCALE_A,
                 sp[7] * SCALE_A);
    w.z = pk4_f8(sp[8] * SCALE_A, sp[9] * SCALE_A, sp[10] * SCALE_A,
                 sp[11] * SCALE_A);
    w.w = pk4_f8(sp[12] * SCALE_A, sp[13] * SCALE_A, sp[14] * SCALE_A,
                 sp[15] * SCALE_A);
    *(uint4*)(Af8 + (size_t)(bx >> 6) * KBLK + (size_t)(by + row) * 64 +
              ch * 16) = w;
  }
  {
    int c = t >> 2, ch = t & 3;
    float v[16];
#pragma unroll
    for (int e = 0; e < 16; ++e) v[e] = sh[(ch * 16 + e) * 65 + c];
    uint4 w;
    w.x = pk4_f8(v[0] * SCALE_A, v[1] * SCALE_A, v[2] * SCALE_A,
                 v[3] * SCALE_A);
    w.y = pk4_f8(v[4] * SCALE_A, v[5] * SCALE_A, v[6] * SCALE_A,
                 v[7] * SCALE_A);
    w.z = pk4_f8(v[8] * SCALE_A, v[9] * SCALE_A, v[10] * SCALE_A,
                 v[11] * SCALE_A);
    w.w = pk4_f8(v[12] * SCALE_A, v[13] * SCALE_A, v[14] * SCALE_A,
                 v[15] * SCALE_A);
    *(uint4*)(Atf8 + (size_t)(by >> 6) * KBLK + (size_t)(bx + c) * 64 +
              ch * 16) = w;
  }
  const int q = t >> 6;
  const int l = t & 63;
  float sy = 0.f, ss_ = 0.f;
  for (int i = 0; i < 16; ++i) {
    int c = q * 16 + i;
    sy += sh[l * 65 + c] * vv[bx + c];
    ss_ += vu[by + c] * sh[c * 65 + l];
  }
  float* red = sh + 64 * 65;
  red[q * 64 + l] = sy;
  red[256 + q * 64 + l] = ss_;
  __syncthreads();
  if (t < 64) {
    float v4 = red[t] + red[64 + t] + red[128 + t] + red[192 + t];
    atomAddF(&y1[by + t], v4);
  } else if (t < 128) {
    int cc = t - 64;
    float v4 = red[256 + cc] + red[256 + 64 + cc] + red[256 + 128 + cc] +
               red[256 + 192 + cc];
    atomAddF(&s1[bx + cc], v4);
  }
}

// ---------------------------------------------------------------------------
// LDS-free fp8 GEMM via MX-scaled 32x32x64 MFMA at unit scales. Register
// double-buffered; no barriers in the K-loop.
static __device__ inline i32x8 ldfrag(const unsigned char* p) {
  i32x4 lo = *(const i32x4*)p;
  i32x4 hi = *(const i32x4*)(p + 16);
  return (i32x8){lo.x, lo.y, lo.z, lo.w, hi.x, hi.y, hi.z, hi.w};
}

__global__ __launch_bounds__(256) void gemm_f8(
    const unsigned char* __restrict__ Ag,
    const unsigned char* __restrict__ Btg,
    unsigned short* __restrict__ Cg, int kLen) {
  const int tid = threadIdx.x;
  const int wave = tid >> 6;
  const int lane = tid & 63;
  const int rowBase = blockIdx.y * 128;
  const int colBase = blockIdx.x * 128;
  const int wr = wave >> 1, wc = wave & 1;
  const int r32 = lane & 31, hh = lane >> 5;
  const int kStart = blockIdx.z * kLen;
  unsigned short* Cout = Cg + (size_t)blockIdx.z * NN * NN;

  f32x16 acc[2][2];
  for (int i = 0; i < 2; ++i)
    for (int j = 0; j < 2; ++j)
      for (int e = 0; e < 16; ++e) acc[i][j][e] = 0.f;

  const unsigned char* aP0 = Ag + (size_t)(kStart >> 6) * KBLK +
                             (size_t)(rowBase + (wr * 2) * 32 + r32) * 64 +
                             hh * 32;
  const unsigned char* aP1 = aP0 + 32 * 64;
  const unsigned char* bP0 = Btg + (size_t)(kStart >> 6) * KBLK +
                             (size_t)(colBase + (wc * 2) * 32 + r32) * 64 +
                             hh * 32;
  const unsigned char* bP1 = bP0 + 32 * 64;

  const int nIter = kLen >> 6;
  i32x8 a0 = ldfrag(aP0), a1 = ldfrag(aP1);
  i32x8 b0 = ldfrag(bP0), b1 = ldfrag(bP1);
  for (int it = 0; it < nIter - 1; ++it) {
    aP0 += KBLK; aP1 += KBLK; bP0 += KBLK; bP1 += KBLK;
    i32x8 na0 = ldfrag(aP0), na1 = ldfrag(aP1);
    i32x8 nb0 = ldfrag(bP0), nb1 = ldfrag(bP1);
    acc[0][0] = __builtin_amdgcn_mfma_scale_f32_32x32x64_f8f6f4(
        a0, b0, acc[0][0], 0, 0, 0, 127, 0, 127);
    acc[0][1] = __builtin_amdgcn_mfma_scale_f32_32x32x64_f8f6f4(
        a0, b1, acc[0][1], 0, 0, 0, 127, 0, 127);
    acc[1][0] = __builtin_amdgcn_mfma_scale_f32_32x32x64_f8f6f4(
        a1, b0, acc[1][0], 0, 0, 0, 127, 0, 127);
    acc[1][1] = __builtin_amdgcn_mfma_scale_f32_32x32x64_f8f6f4(
        a1, b1, acc[1][1], 0, 0, 0, 127, 0, 127);
    a0 = na0; a1 = na1; b0 = nb0; b1 = nb1;
  }
  acc[0][0] = __builtin_amdgcn_mfma_scale_f32_32x32x64_f8f6f4(
      a0, b0, acc[0][0], 0, 0, 0, 127, 0, 127);
  acc[0][1] = __builtin_amdgcn_mfma_scale_f32_32x32x64_f8f6f4(
      a0, b1, acc[0][1], 0, 0, 0, 127, 0, 127);
  acc[1][0] = __builtin_amdgcn_mfma_scale_f32_32x32x64_f8f6f4(
      a1, b0, acc[1][0], 0, 0, 0, 127, 0, 127);
  acc[1][1] = __builtin_amdgcn_mfma_scale_f32_32x32x64_f8f6f4(
      a1, b1, acc[1][1], 0, 0, 0, 127, 0, 127);

  // C/D 32x32 layout: col = lane&31, row = (reg&3) + 8*(reg>>2) + 4*(lane>>5)
  for (int i = 0; i < 2; ++i) {
    int rb = rowBase + wr * 64 + i * 32 + 4 * hh;
    for (int j = 0; j < 2; ++j) {
      int cc = colBase + wc * 64 + j * 32 + r32;
      for (int reg = 0; reg < 16; ++reg) {
        int rr = rb + (reg & 3) + 8 * (reg >> 2);
        Cout[(size_t)rr * NN + cc] = bf16bits(acc[i][j][reg]);
      }
    }
  }
}

// ---------------------------------------------------------------------------
// post1: [0,768)     topk(A2 bf16 partial-sum) + packed fp8 cast -> A2f8
//        [768,1536)  tvec = A.y1 (one wave per row)
//        [1536,1920) concat uemb/iemb -> allE (aliases dead Af8)
__global__ __launch_bounds__(256) void post1(
    const unsigned short* __restrict__ C, int parts,
    const float* __restrict__ A, const float* __restrict__ y1,
    unsigned char* __restrict__ A2f8, int* __restrict__ cnts1,
    int* __restrict__ tIdx1, float* __restrict__ tVal1,
    float* __restrict__ tvec, const float* __restrict__ uemb,
    const float* __restrict__ iemb, float* __restrict__ allE) {
  const int bid = blockIdx.x;
  const int t = threadIdx.x;
  if (bid < 768) {
    int row = bid * 4 + (t >> 6);
    int lane = t & 63;
    float f[48];
    load48_bf(C, parts, row, lane, f);
    // fused packed fp8 cast: f[j*8+e] = col k0+e, k0=(j*64+lane)*8
#pragma unroll
    for (int j = 0; j < 6; ++j) {
      uint2 w;
      w.x = pk4_f8(f[j * 8 + 0] * F8SCALE2, f[j * 8 + 1] * F8SCALE2,
                   f[j * 8 + 2] * F8SCALE2, f[j * 8 + 3] * F8SCALE2);
      w.y = pk4_f8(f[j * 8 + 4] * F8SCALE2, f[j * 8 + 5] * F8SCALE2,
                   f[j * 8 + 6] * F8SCALE2, f[j * 8 + 7] * F8SCALE2);
      size_t addr = (size_t)(j * 8 + (lane >> 3)) * KBLK +
                    (size_t)row * 64 + (lane & 7) * 8;
      *(uint2*)(A2f8 + addr) = w;
    }
    select_compact(f, lane, DESCALE38, 1, &cnts1[row],
                   tIdx1 + (size_t)row * 128, tVal1 + (size_t)row * 128);
  } else if (bid < 1536) {
    int row = (bid - 768) * 4 + (t >> 6);
    int lane = t & 63;
    const float4* rp = (const float4*)(A + (size_t)row * NN);
    const float4* yp = (const float4*)y1;
    float s = 0.f;
#pragma unroll
    for (int j = 0; j < 12; ++j) {
      float4 a = rp[lane + j * 64];
      float4 y = yp[lane + j * 64];
      s += a.x * y.x + a.y * y.y + a.z * y.z + a.w * y.w;
    }
    for (int off = 32; off; off >>= 1) s += __shfl_down(s, off, 64);
    if (lane == 0) tvec[row] = s;
  } else {
    // concat embeddings into allE[NN][DD]; 384 blocks x 256 thr x float4
    int idx = (bid - 1536) * 256 + t;
    int e = idx * 4;
    float4 v = (e < NU * DD) ? *(const float4*)(uemb + e)
                             : *(const float4*)(iemb + (e - NU * DD));
    *(float4*)(allE + e) = v;
  }
}

// ---------------------------------------------------------------------------
// post2: single block -> w0..w3
__global__ __launch_bounds__(256) void post2(
    const float* __restrict__ vu, const float* __restrict__ vv,
    const float* __restrict__ y1, const float* __restrict__ s1,
    const float* __restrict__ tvec, float* __restrict__ wacc) {
  __shared__ float red4[4];
  const int t = threadIdx.x;
  float w0 = row_dot_f32(vu, vv, red4);  __syncthreads();
  float w1 = row_dot_f32(vu, y1, red4);  __syncthreads();
  float w2 = row_dot_f32(s1, y1, red4);  __syncthreads();
  float w3 = row_dot_f32(s1, tvec, red4);
  if (t == 0) { wacc[0] = w0; wacc[1] = w1; wacc[2] = w2; wacc[3] = w3; }
}

// ---------------------------------------------------------------------------
// build_light v2: 256 threads (4 waves).
//   phase A: wv0 loads C part0 / wv2 unpacks C part1 -> LDS (halves the
//            layer-2 load critical path) / wv1 loads A / wv3 stages layer-1
//            list; then wv0+wv1 run the pair-radix selects concurrently.
//   phase B: all 256 threads gather with 2-way k-split (h = t>>7 takes k
//            parity), halving the serial gather chain; LDS-reduce then write.
// Embedding gathers go through the concatenated allE with pre-scaled indices
// (no user/item branch in the inner loop).
__global__ __launch_bounds__(256) void build_light(
    const unsigned short* __restrict__ C, int parts,
    const float* __restrict__ A, const float* __restrict__ allE,
    const float* __restrict__ uemb0, const float* __restrict__ iemb0,
    const float* __restrict__ wacc, const int* __restrict__ cnts1,
    const int* __restrict__ tIdx1, const float* __restrict__ tVal1,
    float* __restrict__ lightOut) {
  __shared__ int l0i[128];
  __shared__ float l0v[128];
  __shared__ int l2i[128];
  __shared__ float l2v[128];
  __shared__ int s1i[128];
  __shared__ float s1v[128];
  __shared__ int lcnt[4];  // [0]=layer0, [1]=layer2, [2]=layer1 count
  __shared__ float p1s[64 * 49];  // part-1 staging, stride 49 (conflict-free)
  __shared__ float redb[128];

  const int row = blockIdx.x;
  const int t = threadIdx.x;
  const int wv = t >> 6;
  const int lane = t & 63;

  float f[48];
  if (wv == 0) {
    load48_bf(C, 1, row, lane, f);  // part 0 only
  } else if (wv == 1) {
    load48_f32(A, row, lane, f);
  } else if (wv == 2) {
    if (parts > 1) {
      const uint4* rp = (const uint4*)(C + (size_t)NN * NN + (size_t)row * NN);
#pragma unroll
      for (int j = 0; j < 6; ++j) {
        uint4 q = rp[lane + j * 64];
        unsigned uu[4] = {q.x, q.y, q.z, q.w};
#pragma unroll
        for (int e = 0; e < 4; ++e) {
          p1s[lane * 49 + j * 8 + e * 2] = __uint_as_float(uu[e] << 16);
          p1s[lane * 49 + j * 8 + e * 2 + 1] =
              __uint_as_float(uu[e] & 0xffff0000u);
        }
      }
    }
  } else {
    int c1 = cnts1[row];
    if (lane == 0) lcnt[2] = c1;
    for (int k = lane; k < c1; k += 64) {
      s1i[k] = tIdx1[(size_t)row * 128 + k];
      s1v[k] = tVal1[(size_t)row * 128 + k];
    }
  }
  __syncthreads();
  if (wv == 0) {
    if (parts > 1) {
#pragma unroll
      for (int r = 0; r < 48; ++r) f[r] += p1s[lane * 49 + r];
    }
    select_compact(f, lane, DESCALE38, 1, &lcnt[1], l2i, l2v);
  } else if (wv == 1) {
    select_compact(f, lane, 1.0f, 0, &lcnt[0], l0i, l0v);
  }
  __syncthreads();

  float w0 = wacc[0], w1 = wacc[1], w2 = wacc[2], w3 = wacc[3];
  float ss = w0 + w1 + w2 + w3;
  w0 /= ss; w1 /= ss; w2 /= ss; w3 /= ss;
  float m = fmaxf(fmaxf(w0, w1), fmaxf(w2, w3));
  float e0 = expf(w0 - m), e1 = expf(w1 - m), e2 = expf(w2 - m),
        e3 = expf(w3 - m);
  float se = e0 + e1 + e2 + e3;
  float aw0 = e0 / se, aw1 = e1 / se, aw2 = e2 / se, aw3 = e3 / se;
  float aw4 = GAMMA_F * (aw1 + aw2 + aw3);

  const int d = t & 127;
  const int h = t >> 7;
  const int cl0 = lcnt[0], cl2 = lcnt[1], cl1 = lcnt[2];
  float acc = 0.f;
  {
    float la = 0.f;
    for (int k = h; k < cl0; k += 2) la += l0v[k] * allE[l0i[k] + d];
    acc += aw1 * la;
  }
  {
    float la = 0.f;
    for (int k = h; k < cl1; k += 2) la += s1v[k] * allE[s1i[k] + d];
    acc += aw2 * la;
  }
  {
    float la = 0.f;
    for (int k = h; k < cl2; k += 2) la += l2v[k] * allE[l2i[k] + d];
    acc += aw3 * la;
  }
  if (h == 1) redb[d] = acc;
  __syncthreads();
  if (h == 0) {
    float e0v = row < NU ? uemb0[(size_t)row * DD + d]
                         : iemb0[(size_t)(row - NU) * DD + d];
    float tot = acc + redb[d] + aw0 * allE[(row << 7) + d] + aw4 * e0v;
    lightOut[(size_t)row * DD + d] = tot;
  }
}

__global__ __launch_bounds__(256) void out_dot(const int* __restrict__ users,
                                               const int* __restrict__ items,
                                               const float* __restrict__ lightOut,
                                               float* __restrict__ out) {
  int b = blockIdx.x * 4 + (threadIdx.x >> 6);
  int lane = threadIdx.x & 63;
  const float* up = lightOut + (size_t)users[b] * DD;
  const float* ip = lightOut + (size_t)(NU + items[b]) * DD;
  float s = up[lane] * ip[lane] + up[lane + 64] * ip[lane + 64];
  for (int off = 32; off; off >>= 1) s += __shfl_down(s, off, 64);
  if (lane == 0) out[b] = s;
}

// ---------------------------------------------------------------------------
extern "C" void kernel_launch(void* const* d_in, const int* in_sizes, int n_in,
                              void* d_out, int out_size, void* d_ws,
                              size_t ws_size, hipStream_t stream) {
  const int* users = (const int*)d_in[0];
  const int* items = (const int*)d_in[1];
  const float* A = (const float*)d_in[2];
  const float* uemb = (const float*)d_in[3];
  const float* iemb = (const float*)d_in[4];
  const float* uemb0 = (const float*)d_in[5];
  const float* iemb0 = (const float*)d_in[6];
  const float* vu = (const float*)d_in[7];
  const float* vv = (const float*)d_in[8];
  float* out = (float*)d_out;

  char* ws = (char*)d_ws;
  size_t off = 0;
  auto alloc = [&](size_t bytes) -> void* {
    void* p = ws + off;
    off += (bytes + 255) & ~(size_t)255;
    return p;
  };
  unsigned char* Af8 = (unsigned char*)alloc((size_t)NN * NN);
  unsigned char* Atf8 = (unsigned char*)alloc((size_t)NN * NN);
  unsigned char* A2f8 = (unsigned char*)alloc((size_t)NN * NN);
  float* y1 = (float*)alloc((size_t)NN * 4);   // contiguous with s1
  float* s1 = (float*)alloc((size_t)NN * 4);
  float* tvec = (float*)alloc((size_t)NN * 4);
  float* wacc = (float*)alloc(256);
  int* cnts1 = (int*)alloc((size_t)NN * 4);
  int* tIdx1 = (int*)alloc((size_t)NN * 128 * 4);
  float* tVal1 = (float*)alloc((size_t)NN * 128 * 4);
  float* lightOut = (float*)alloc((size_t)NN * DD * 4);

  // allE (NN*DD fp32 = 1.5 MB) aliases Af8 (9.4 MB): Af8 is dead after
  // gemm#1 (step 3); post1 (step 4) writes allE; build_light (step 7) reads.
  float* allE = (float*)Af8;

  const size_t cBytes = (size_t)NN * NN * 2;  // bf16 partials
  int kParts = (ws_size >= off + 2 * cBytes + 512) ? 2 : 1;
  unsigned short* C = (unsigned short*)alloc((size_t)kParts * cBytes);
  const int kLen = NN / kParts;

  // 1) zero y1/s1 (contiguous 2*NN floats)
  hipMemsetAsync(y1, 0, (size_t)2 * NN * 4, stream);
  // 2) prep: A -> packed fp8 (straight+transposed) + y1/s1 partials
  prep<<<2304, 256, 0, stream>>>(A, vu, vv, Af8, Atf8, y1, s1);
  // 3) A2 = A*A (LDS-free MX fp8 MFMA, bf16 partials x2)
  gemm_f8<<<dim3(24, 24, kParts), 256, 0, stream>>>(Af8, Atf8, C, kLen);
  // 4) post1: topk(A2)+packed fp8 cast | tvec = A.y1 | emb concat -> allE
  post1<<<1920, 256, 0, stream>>>(C, kParts, A, y1, A2f8, cnts1, tIdx1,
                                  tVal1, tvec, uemb, iemb, allE);
  // 5) A3 = A2*A (overwrite partials)
  gemm_f8<<<dim3(24, 24, kParts), 256, 0, stream>>>(A2f8, Atf8, C, kLen);
  // 6) post2: w0..w3 (single block)
  post2<<<1, 256, 0, stream>>>(vu, vv, y1, s1, tvec, wacc);
  // 7) build_light v2: 4-wave blocks, split loads, pair-radix, k-split gather
  build_light<<<NN, 256, 0, stream>>>(C, kParts, A, allE, uemb0, iemb0, wacc,
                                      cnts1, tIdx1, tVal1, lightOut);
  // 8) gather dots
  out_dot<<<BB / 4, 256, 0, stream>>>(users, items, lightOut, out);
}

// Round 2
// 302.432 us; speedup vs baseline: 1.0838x; 1.0838x over previous
//
#include <hip/hip_runtime.h>
#include <hip/hip_fp8.h>
#include <math.h>

#define NN 3072
#define NU 1024
#define NI 2048
#define DD 128
#define BB 8192
#define GAMMA_F 0.2f

#define SCALE_A 524288.0f                // 2^19
#define F8SCALE2 1.9073486328125e-06f    // 2^-19  (C*2^38 -> A2*2^19 for fp8)
#define DESCALE38 3.637978807091713e-12f // 2^-38  (C -> true A^k values)

// packed fp8 layout: [k/64][row][k%64]; one k-block = NN rows x 64 B
#define KBLK ((size_t)NN * 64)

typedef __attribute__((ext_vector_type(4))) float f32x4;
typedef __attribute__((ext_vector_type(16))) float f32x16;
typedef __attribute__((ext_vector_type(4))) int i32x4;
typedef __attribute__((ext_vector_type(8))) int i32x8;

static __device__ inline unsigned short bf16bits(float x) {
  union { unsigned u; float f; } cv;
  cv.f = x;
  unsigned r = cv.u + 0x7fff + ((cv.u >> 16) & 1);  // RNE
  return (unsigned short)(r >> 16);
}

// pack 4 floats -> 4 fp8 e4m3 (OCP) bytes
static __device__ inline unsigned pk4_f8(float a, float b, float c, float d) {
#if defined(__has_builtin)
#if __has_builtin(__builtin_amdgcn_cvt_pk_fp8_f32)
  int p = __builtin_amdgcn_cvt_pk_fp8_f32(a, b, 0, false);
  p = __builtin_amdgcn_cvt_pk_fp8_f32(c, d, p, true);
  return (unsigned)p;
#else
  return (unsigned)__hip_fp8_e4m3(a).__x | ((unsigned)__hip_fp8_e4m3(b).__x << 8) |
         ((unsigned)__hip_fp8_e4m3(c).__x << 16) |
         ((unsigned)__hip_fp8_e4m3(d).__x << 24);
#endif
#else
  return (unsigned)__hip_fp8_e4m3(a).__x | ((unsigned)__hip_fp8_e4m3(b).__x << 8) |
         ((unsigned)__hip_fp8_e4m3(c).__x << 16) |
         ((unsigned)__hip_fp8_e4m3(d).__x << 24);
#endif
}

static __device__ inline void atomAddF(float* p, float v) {
#if defined(__has_builtin)
#if __has_builtin(__builtin_amdgcn_global_atomic_fadd_f32)
  __builtin_amdgcn_global_atomic_fadd_f32(
      (__attribute__((address_space(1))) float*)p, v);
#else
  unsafeAtomicAdd(p, v);
#endif
#else
  unsafeAtomicAdd(p, v);
#endif
}

static __device__ inline float block_sum(float s, float* red4) {
  int tid = threadIdx.x;
  for (int off = 32; off; off >>= 1) s += __shfl_down(s, off, 64);
  if ((tid & 63) == 0) red4[tid >> 6] = s;
  __syncthreads();
  return red4[0] + red4[1] + red4[2] + red4[3];
}

static __device__ inline float row_dot_f32(const float* __restrict__ a,
                                           const float* __restrict__ b,
                                           float* red4) {
  const float4* ap = (const float4*)a;
  const float4* bp = (const float4*)b;
  float s = 0.f;
  for (int j = threadIdx.x; j < NN / 4; j += 256) {
    float4 x = ap[j], y = bp[j];
    s += x.x * y.x + x.y * y.y + x.z * y.z + x.w * y.w;
  }
  return block_sum(s, red4);
}

// ---------------------------------------------------------------------------
// topk loaders: fill f[48] with this row's values (one wave, 48 vals/lane).
static __device__ inline void load48_bf(const unsigned short* __restrict__ b0,
                                        int parts, int row, int lane,
                                        float* f) {
  const uint4* r0 = (const uint4*)(b0 + (size_t)row * NN);
#pragma unroll
  for (int j = 0; j < 6; ++j) {
    uint4 q = r0[lane + j * 64];
    unsigned uu[4] = {q.x, q.y, q.z, q.w};
#pragma unroll
    for (int e = 0; e < 4; ++e) {
      f[j * 8 + e * 2] = __uint_as_float(uu[e] << 16);
      f[j * 8 + e * 2 + 1] = __uint_as_float(uu[e] & 0xffff0000u);
    }
  }
  for (int p = 1; p < parts; ++p) {
    const uint4* rp = (const uint4*)(b0 + (size_t)p * NN * NN + (size_t)row * NN);
#pragma unroll
    for (int j = 0; j < 6; ++j) {
      uint4 q = rp[lane + j * 64];
      unsigned uu[4] = {q.x, q.y, q.z, q.w};
#pragma unroll
      for (int e = 0; e < 4; ++e) {
        f[j * 8 + e * 2] += __uint_as_float(uu[e] << 16);
        f[j * 8 + e * 2 + 1] += __uint_as_float(uu[e] & 0xffff0000u);
      }
    }
  }
}

static __device__ inline void load48_f32(const float* __restrict__ A, int row,
                                         int lane, float* f) {
  const float4* r0 = (const float4*)(A + (size_t)row * NN);
#pragma unroll
  for (int j = 0; j < 12; ++j) {
    float4 a = r0[lane + j * 64];
    f[j * 4 + 0] = a.x; f[j * 4 + 1] = a.y;
    f[j * 4 + 2] = a.z; f[j * 4 + 3] = a.w;
  }
}

// ---------------------------------------------------------------------------
// select top-64 of the wave's 64x48 values. Radix on bits [30..16] resolved
// TWO bits per step (counts are monotone c3<=c2<=c1, so "largest 2-bit
// pattern with count>=64" == two greedy single-bit steps) with butterfly
// shfl_xor reduces (all lanes end with the total -> no broadcast). Compact
// (idx*DD, val*scale) into out arrays (128 slots; LDS or global).
static __device__ void select_compact(const float* f, int lane, float descale,
                                      int bf, int* __restrict__ outCnt,
                                      int* __restrict__ outIdx,
                                      float* __restrict__ outVal) {
  unsigned bor = 0, band = 0xffffffffu;
#pragma unroll
  for (int r = 0; r < 48; ++r) {
    unsigned k = __float_as_uint(f[r]);
    bor |= k; band &= k;
  }
  for (int off = 32; off; off >>= 1) {
    bor |= (unsigned)__shfl_xor((int)bor, off, 64);
    band &= (unsigned)__shfl_xor((int)band, off, 64);
  }
  unsigned diff = bor ^ band;
  int hi = diff ? (31 - __clz(diff)) : 16;
  if (hi < 16) hi = 16;
  if (hi > 30) hi = 30;
  unsigned t = band & ~((2u << hi) - 1u);

  int b = hi;
  while (b >= 17) {
    unsigned base = 1u << (b - 1);
    unsigned cand1 = t | base;
    unsigned cand2 = t | (base << 1);
    unsigned cand3 = cand2 | base;
    int c1 = 0, c2 = 0, c3 = 0;
#pragma unroll
    for (int r = 0; r < 48; ++r) {
      unsigned k = __float_as_uint(f[r]);
      c1 += (k >= cand1) ? 1 : 0;
      c2 += (k >= cand2) ? 1 : 0;
      c3 += (k >= cand3) ? 1 : 0;
    }
    for (int off = 32; off; off >>= 1) {
      c1 += __shfl_xor(c1, off, 64);
      c2 += __shfl_xor(c2, off, 64);
      c3 += __shfl_xor(c3, off, 64);
    }
    if (c3 >= 64) t = cand3;
    else if (c2 >= 64) t = cand2;
    else if (c1 >= 64) t = cand1;
    b -= 2;
  }
  if (b == 16) {
    unsigned cand = t | (1u << 16);
    int c = 0;
#pragma unroll
    for (int r = 0; r < 48; ++r) c += (__float_as_uint(f[r]) >= cand) ? 1 : 0;
    for (int off = 32; off; off >>= 1) c += __shfl_xor(c, off, 64);
    if (c >= 64) t = cand;
  }

  int basec = 0;
#pragma unroll
  for (int r = 0; r < 48; ++r) {
    bool keep = __float_as_uint(f[r]) >= t;
    unsigned long long m = __ballot(keep);
    if (keep) {
      int pos = basec + __popcll(m & ((1ull << lane) - 1ull));
      if (pos < 128) {
        int col = bf ? ((r >> 3) * 512 + lane * 8 + (r & 7))
                     : ((r >> 2) * 256 + lane * 4 + (r & 3));
        outIdx[pos] = col << 7;  // pre-scaled by DD for gather addressing
        outVal[pos] = f[r] * descale;
      }
    }
    basec += __popcll(m);
  }
  if (lane == 0) *outCnt = basec < 128 ? basec : 128;
}

// ---------------------------------------------------------------------------
// prep: A -> fp8 PACKED (straight + transposed, x2^19) + fused y1/s1 matvec
// partials. grid 2304 (48x48 tiles of 64x64).
__global__ __launch_bounds__(256) void prep(
    const float* __restrict__ A, const float* __restrict__ vu,
    const float* __restrict__ vv, unsigned char* __restrict__ Af8,
    unsigned char* __restrict__ Atf8, float* __restrict__ y1,
    float* __restrict__ s1) {
  __shared__ float sh[64 * 65 + 512];
  const int bid = blockIdx.x;
  const int t = threadIdx.x;
  const int bx = (bid % 48) * 64, by = (bid / 48) * 64;
  const int rr = t >> 4;
  const int c4 = (t & 15) * 4;
  for (int it = 0; it < 4; ++it) {
    int r = rr + it * 16;
    float4 val = *(const float4*)(A + (size_t)(by + r) * NN + bx + c4);
    sh[r * 65 + c4] = val.x; sh[r * 65 + c4 + 1] = val.y;
    sh[r * 65 + c4 + 2] = val.z; sh[r * 65 + c4 + 3] = val.w;
  }
  __syncthreads();
  {
    int row = t >> 2, ch = t & 3;
    const float* sp = &sh[row * 65 + ch * 16];
    uint4 w;
    w.x = pk4_f8(sp[0] * SCALE_A, sp[1] * SCALE_A, sp[2] * SCALE_A,
                 sp[3] * SCALE_A);
    w.y = pk4_f8(sp[4] * SCALE_A, sp[5] * SCALE_A, sp[6] * SCALE_A,
                 sp[7] * SCALE_A);
    w.z = pk4_f8(sp[8] * SCALE_A, sp[9] * SCALE_A, sp[10] * SCALE_A,
                 sp[11] * SCALE_A);
    w.w = pk4_f8(sp[12] * SCALE_A, sp[13] * SCALE_A, sp[14] * SCALE_A,
                 sp[15] * SCALE_A);
    *(uint4*)(Af8 + (size_t)(bx >> 6) * KBLK + (size_t)(by + row) * 64 +
              ch * 16) = w;
  }
  {
    int c = t >> 2, ch = t & 3;
    float v[16];
#pragma unroll
    for (int e = 0; e < 16; ++e) v[e] = sh[(ch * 16 + e) * 65 + c];
    uint4 w;
    w.x = pk4_f8(v[0] * SCALE_A, v[1] * SCALE_A, v[2] * SCALE_A,
                 v[3] * SCALE_A);
    w.y = pk4_f8(v[4] * SCALE_A, v[5] * SCALE_A, v[6] * SCALE_A,
                 v[7] * SCALE_A);
    w.z = pk4_f8(v[8] * SCALE_A, v[9] * SCALE_A, v[10] * SCALE_A,
                 v[11] * SCALE_A);
    w.w = pk4_f8(v[12] * SCALE_A, v[13] * SCALE_A, v[14] * SCALE_A,
                 v[15] * SCALE_A);
    *(uint4*)(Atf8 + (size_t)(by >> 6) * KBLK + (size_t)(bx + c) * 64 +
              ch * 16) = w;
  }
  const int q = t >> 6;
  const int l = t & 63;
  float sy = 0.f, ss_ = 0.f;
  for (int i = 0; i < 16; ++i) {
    int c = q * 16 + i;
    sy += sh[l * 65 + c] * vv[bx + c];
    ss_ += vu[by + c] * sh[c * 65 + l];
  }
  float* red = sh + 64 * 65;
  red[q * 64 + l] = sy;
  red[256 + q * 64 + l] = ss_;
  __syncthreads();
  if (t < 64) {
    float v4 = red[t] + red[64 + t] + red[128 + t] + red[192 + t];
    atomAddF(&y1[by + t], v4);
  } else if (t < 128) {
    int cc = t - 64;
    float v4 = red[256 + cc] + red[256 + 64 + cc] + red[256 + 128 + cc] +
               red[256 + 192 + cc];
    atomAddF(&s1[bx + cc], v4);
  }
}

// ---------------------------------------------------------------------------
// LDS-free fp8 GEMM via MX-scaled 32x32x64 MFMA at unit scales. Register
// double-buffered; no barriers in the K-loop.
static __device__ inline i32x8 ldfrag(const unsigned char* p) {
  i32x4 lo = *(const i32x4*)p;
  i32x4 hi = *(const i32x4*)(p + 16);
  return (i32x8){lo.x, lo.y, lo.z, lo.w, hi.x, hi.y, hi.z, hi.w};
}

__global__ __launch_bounds__(256) void gemm_f8(
    const unsigned char* __restrict__ Ag,
    const unsigned char* __restrict__ Btg,
    unsigned short* __restrict__ Cg, int kLen) {
  const int tid = threadIdx.x;
  const int wave = tid >> 6;
  const int lane = tid & 63;
  const int rowBase = blockIdx.y * 128;
  const int colBase = blockIdx.x * 128;
  const int wr = wave >> 1, wc = wave & 1;
  const int r32 = lane & 31, hh = lane >> 5;
  const int kStart = blockIdx.z * kLen;
  unsigned short* Cout = Cg + (size_t)blockIdx.z * NN * NN;

  f32x16 acc[2][2];
  for (int i = 0; i < 2; ++i)
    for (int j = 0; j < 2; ++j)
      for (int e = 0; e < 16; ++e) acc[i][j][e] = 0.f;

  const unsigned char* aP0 = Ag + (size_t)(kStart >> 6) * KBLK +
                             (size_t)(rowBase + (wr * 2) * 32 + r32) * 64 +
                             hh * 32;
  const unsigned char* aP1 = aP0 + 32 * 64;
  const unsigned char* bP0 = Btg + (size_t)(kStart >> 6) * KBLK +
                             (size_t)(colBase + (wc * 2) * 32 + r32) * 64 +
                             hh * 32;
  const unsigned char* bP1 = bP0 + 32 * 64;

  const int nIter = kLen >> 6;
  i32x8 a0 = ldfrag(aP0), a1 = ldfrag(aP1);
  i32x8 b0 = ldfrag(bP0), b1 = ldfrag(bP1);
  for (int it = 0; it < nIter - 1; ++it) {
    aP0 += KBLK; aP1 += KBLK; bP0 += KBLK; bP1 += KBLK;
    i32x8 na0 = ldfrag(aP0), na1 = ldfrag(aP1);
    i32x8 nb0 = ldfrag(bP0), nb1 = ldfrag(bP1);
    acc[0][0] = __builtin_amdgcn_mfma_scale_f32_32x32x64_f8f6f4(
        a0, b0, acc[0][0], 0, 0, 0, 127, 0, 127);
    acc[0][1] = __builtin_amdgcn_mfma_scale_f32_32x32x64_f8f6f4(
        a0, b1, acc[0][1], 0, 0, 0, 127, 0, 127);
    acc[1][0] = __builtin_amdgcn_mfma_scale_f32_32x32x64_f8f6f4(
        a1, b0, acc[1][0], 0, 0, 0, 127, 0, 127);
    acc[1][1] = __builtin_amdgcn_mfma_scale_f32_32x32x64_f8f6f4(
        a1, b1, acc[1][1], 0, 0, 0, 127, 0, 127);
    a0 = na0; a1 = na1; b0 = nb0; b1 = nb1;
  }
  acc[0][0] = __builtin_amdgcn_mfma_scale_f32_32x32x64_f8f6f4(
      a0, b0, acc[0][0], 0, 0, 0, 127, 0, 127);
  acc[0][1] = __builtin_amdgcn_mfma_scale_f32_32x32x64_f8f6f4(
      a0, b1, acc[0][1], 0, 0, 0, 127, 0, 127);
  acc[1][0] = __builtin_amdgcn_mfma_scale_f32_32x32x64_f8f6f4(
      a1, b0, acc[1][0], 0, 0, 0, 127, 0, 127);
  acc[1][1] = __builtin_amdgcn_mfma_scale_f32_32x32x64_f8f6f4(
      a1, b1, acc[1][1], 0, 0, 0, 127, 0, 127);

  // C/D 32x32 layout: col = lane&31, row = (reg&3) + 8*(reg>>2) + 4*(lane>>5)
  for (int i = 0; i < 2; ++i) {
    int rb = rowBase + wr * 64 + i * 32 + 4 * hh;
    for (int j = 0; j < 2; ++j) {
      int cc = colBase + wc * 64 + j * 32 + r32;
      for (int reg = 0; reg < 16; ++reg) {
        int rr = rb + (reg & 3) + 8 * (reg >> 2);
        Cout[(size_t)rr * NN + cc] = bf16bits(acc[i][j][reg]);
      }
    }
  }
}

// ---------------------------------------------------------------------------
// post1: [0,768)     topk(A2 bf16 partial-sum) + packed fp8 cast -> A2f8
//        [768,1536)  tvec = A.y1 (one wave per row)
//        [1536,1920) concat uemb/iemb -> allE (aliases dead Af8)
__global__ __launch_bounds__(256) void post1(
    const unsigned short* __restrict__ C, int parts,
    const float* __restrict__ A, const float* __restrict__ y1,
    unsigned char* __restrict__ A2f8, int* __restrict__ cnts1,
    int* __restrict__ tIdx1, float* __restrict__ tVal1,
    float* __restrict__ tvec, const float* __restrict__ uemb,
    const float* __restrict__ iemb, float* __restrict__ allE) {
  const int bid = blockIdx.x;
  const int t = threadIdx.x;
  if (bid < 768) {
    int row = bid * 4 + (t >> 6);
    int lane = t & 63;
    float f[48];
    load48_bf(C, parts, row, lane, f);
    // fused packed fp8 cast: f[j*8+e] = col k0+e, k0=(j*64+lane)*8
#pragma unroll
    for (int j = 0; j < 6; ++j) {
      uint2 w;
      w.x = pk4_f8(f[j * 8 + 0] * F8SCALE2, f[j * 8 + 1] * F8SCALE2,
                   f[j * 8 + 2] * F8SCALE2, f[j * 8 + 3] * F8SCALE2);
      w.y = pk4_f8(f[j * 8 + 4] * F8SCALE2, f[j * 8 + 5] * F8SCALE2,
                   f[j * 8 + 6] * F8SCALE2, f[j * 8 + 7] * F8SCALE2);
      size_t addr = (size_t)(j * 8 + (lane >> 3)) * KBLK +
                    (size_t)row * 64 + (lane & 7) * 8;
      *(uint2*)(A2f8 + addr) = w;
    }
    select_compact(f, lane, DESCALE38, 1, &cnts1[row],
                   tIdx1 + (size_t)row * 128, tVal1 + (size_t)row * 128);
  } else if (bid < 1536) {
    int row = (bid - 768) * 4 + (t >> 6);
    int lane = t & 63;
    const float4* rp = (const float4*)(A + (size_t)row * NN);
    const float4* yp = (const float4*)y1;
    float s = 0.f;
#pragma unroll
    for (int j = 0; j < 12; ++j) {
      float4 a = rp[lane + j * 64];
      float4 y = yp[lane + j * 64];
      s += a.x * y.x + a.y * y.y + a.z * y.z + a.w * y.w;
    }
    for (int off = 32; off; off >>= 1) s += __shfl_down(s, off, 64);
    if (lane == 0) tvec[row] = s;
  } else {
    // concat embeddings into allE[NN][DD]; 384 blocks x 256 thr x float4
    int idx = (bid - 1536) * 256 + t;
    int e = idx * 4;
    float4 v = (e < NU * DD) ? *(const float4*)(uemb + e)
                             : *(const float4*)(iemb + (e - NU * DD));
    *(float4*)(allE + e) = v;
  }
}

// ---------------------------------------------------------------------------
// post2: single block -> w0..w3
__global__ __launch_bounds__(256) void post2(
    const float* __restrict__ vu, const float* __restrict__ vv,
    const float* __restrict__ y1, const float* __restrict__ s1,
    const float* __restrict__ tvec, float* __restrict__ wacc) {
  __shared__ float red4[4];
  const int t = threadIdx.x;
  float w0 = row_dot_f32(vu, vv, red4);  __syncthreads();
  float w1 = row_dot_f32(vu, y1, red4);  __syncthreads();
  float w2 = row_dot_f32(s1, y1, red4);  __syncthreads();
  float w3 = row_dot_f32(s1, tvec, red4);
  if (t == 0) { wacc[0] = w0; wacc[1] = w1; wacc[2] = w2; wacc[3] = w3; }
}

// ---------------------------------------------------------------------------
// build_light v3: 128 threads (2 waves), latency-optimized gather.
//   - attention weights folded into list VALUES at select/stage time ->
//     single accumulator set across all 3 layers.
//   - each list padded to a multiple of 8 (idx=0,val=0 no-ops) -> gather
//     inner loop is an exact 8x unroll with 8 independent global loads in
//     flight (the v1 loop had ~1 load in flight; this was the 75 us).
//   - wave0: select layer2 from C partial sums; wave1: select layer0 from A;
//     layer1 list staged by all 128 threads at entry (overlaps selects).
__global__ __launch_bounds__(128) void build_light(
    const unsigned short* __restrict__ C, int parts,
    const float* __restrict__ A, const float* __restrict__ allE,
    const float* __restrict__ uemb0, const float* __restrict__ iemb0,
    const float* __restrict__ wacc, const int* __restrict__ cnts1,
    const int* __restrict__ tIdx1, const float* __restrict__ tVal1,
    float* __restrict__ lightOut) {
  __shared__ int li[3][128];
  __shared__ float lv[3][128];
  __shared__ int lcnt[3];

  const int row = blockIdx.x;
  const int t = threadIdx.x;
  const int lane = t & 63;

  // softmax weights (uniform across block; recomputed per thread, cheap)
  float w0 = wacc[0], w1 = wacc[1], w2 = wacc[2], w3 = wacc[3];
  float ss = w0 + w1 + w2 + w3;
  w0 /= ss; w1 /= ss; w2 /= ss; w3 /= ss;
  float m = fmaxf(fmaxf(w0, w1), fmaxf(w2, w3));
  float ex0 = expf(w0 - m), ex1 = expf(w1 - m), ex2 = expf(w2 - m),
        ex3 = expf(w3 - m);
  float se = ex0 + ex1 + ex2 + ex3;
  float aw0 = ex0 / se, aw1 = ex1 / se, aw2 = ex2 / se, aw3 = ex3 / se;
  float aw4 = GAMMA_F * (aw1 + aw2 + aw3);

  // stage layer-1 list (pre-scaled by aw2); load all 128 slots, pad later
  int c1 = cnts1[row];
  li[1][t] = tIdx1[(size_t)row * 128 + t];
  lv[1][t] = aw2 * tVal1[(size_t)row * 128 + t];
  if (t == 0) lcnt[1] = c1;

  {
    float f[48];
    if (t < 64) {
      load48_bf(C, parts, row, lane, f);
      select_compact(f, lane, DESCALE38 * aw3, 1, &lcnt[2], li[2], lv[2]);
    } else {
      load48_f32(A, row, lane, f);
      select_compact(f, lane, aw1, 0, &lcnt[0], li[0], lv[0]);
    }
  }
  __syncthreads();
  // pad each list to a multiple of 8 with (idx=0, val=0)
  if (t < 24) {
    int j = t >> 3, e = t & 7;
    int c = lcnt[j];
    int s = c + e;
    if (s < ((c + 7) & ~7) && s < 128) { li[j][s] = 0; lv[j][s] = 0.f; }
  }
  __syncthreads();

  const int d = t;
  float p0 = 0.f, p1 = 0.f, p2 = 0.f, p3 = 0.f;
#pragma unroll 1
  for (int j = 0; j < 3; ++j) {
    const int cp = (lcnt[j] + 7) & ~7;
    const int* ji = li[j];
    const float* jv = lv[j];
    for (int k = 0; k < cp; k += 8) {
      int i0 = ji[k + 0], i1 = ji[k + 1], i2 = ji[k + 2], i3 = ji[k + 3];
      int i4 = ji[k + 4], i5 = ji[k + 5], i6 = ji[k + 6], i7 = ji[k + 7];
      float v0 = jv[k + 0], v1 = jv[k + 1], v2 = jv[k + 2], v3 = jv[k + 3];
      float v4 = jv[k + 4], v5 = jv[k + 5], v6 = jv[k + 6], v7 = jv[k + 7];
      float g0 = allE[i0 + d], g1 = allE[i1 + d];
      float g2 = allE[i2 + d], g3 = allE[i3 + d];
      float g4 = allE[i4 + d], g5 = allE[i5 + d];
      float g6 = allE[i6 + d], g7 = allE[i7 + d];
      p0 += v0 * g0;
      p1 += v1 * g1;
      p2 += v2 * g2;
      p3 += v3 * g3;
      p0 += v4 * g4;
      p1 += v5 * g5;
      p2 += v6 * g6;
      p3 += v7 * g7;
    }
  }
  float e0v = row < NU ? uemb0[(size_t)row * DD + d]
                       : iemb0[(size_t)(row - NU) * DD + d];
  float tot =
      aw0 * allE[(row << 7) + d] + aw4 * e0v + ((p0 + p1) + (p2 + p3));
  lightOut[(size_t)row * DD + d] = tot;
}

__global__ __launch_bounds__(256) void out_dot(const int* __restrict__ users,
                                               const int* __restrict__ items,
                                               const float* __restrict__ lightOut,
                                               float* __restrict__ out) {
  int b = blockIdx.x * 4 + (threadIdx.x >> 6);
  int lane = threadIdx.x & 63;
  const float* up = lightOut + (size_t)users[b] * DD;
  const float* ip = lightOut + (size_t)(NU + items[b]) * DD;
  float s = up[lane] * ip[lane] + up[lane + 64] * ip[lane + 64];
  for (int off = 32; off; off >>= 1) s += __shfl_down(s, off, 64);
  if (lane == 0) out[b] = s;
}

// ---------------------------------------------------------------------------
extern "C" void kernel_launch(void* const* d_in, const int* in_sizes, int n_in,
                              void* d_out, int out_size, void* d_ws,
                              size_t ws_size, hipStream_t stream) {
  const int* users = (const int*)d_in[0];
  const int* items = (const int*)d_in[1];
  const float* A = (const float*)d_in[2];
  const float* uemb = (const float*)d_in[3];
  const float* iemb = (const float*)d_in[4];
  const float* uemb0 = (const float*)d_in[5];
  const float* iemb0 = (const float*)d_in[6];
  const float* vu = (const float*)d_in[7];
  const float* vv = (const float*)d_in[8];
  float* out = (float*)d_out;

  char* ws = (char*)d_ws;
  size_t off = 0;
  auto alloc = [&](size_t bytes) -> void* {
    void* p = ws + off;
    off += (bytes + 255) & ~(size_t)255;
    return p;
  };
  unsigned char* Af8 = (unsigned char*)alloc((size_t)NN * NN);
  unsigned char* Atf8 = (unsigned char*)alloc((size_t)NN * NN);
  unsigned char* A2f8 = (unsigned char*)alloc((size_t)NN * NN);
  float* y1 = (float*)alloc((size_t)NN * 4);   // contiguous with s1
  float* s1 = (float*)alloc((size_t)NN * 4);
  float* tvec = (float*)alloc((size_t)NN * 4);
  float* wacc = (float*)alloc(256);
  int* cnts1 = (int*)alloc((size_t)NN * 4);
  int* tIdx1 = (int*)alloc((size_t)NN * 128 * 4);
  float* tVal1 = (float*)alloc((size_t)NN * 128 * 4);
  float* lightOut = (float*)alloc((size_t)NN * DD * 4);

  // allE (NN*DD fp32 = 1.5 MB) aliases Af8 (9.4 MB): Af8 is dead after
  // gemm#1 (step 3); post1 (step 4) writes allE; build_light (step 7) reads.
  float* allE = (float*)Af8;

  const size_t cBytes = (size_t)NN * NN * 2;  // bf16 partials
  int kParts = (ws_size >= off + 2 * cBytes + 512) ? 2 : 1;
  unsigned short* C = (unsigned short*)alloc((size_t)kParts * cBytes);
  const int kLen = NN / kParts;

  // 1) zero y1/s1 (contiguous 2*NN floats)
  hipMemsetAsync(y1, 0, (size_t)2 * NN * 4, stream);
  // 2) prep: A -> packed fp8 (straight+transposed) + y1/s1 partials
  prep<<<2304, 256, 0, stream>>>(A, vu, vv, Af8, Atf8, y1, s1);
  // 3) A2 = A*A (LDS-free MX fp8 MFMA, bf16 partials x2)
  gemm_f8<<<dim3(24, 24, kParts), 256, 0, stream>>>(Af8, Atf8, C, kLen);
  // 4) post1: topk(A2)+packed fp8 cast | tvec = A.y1 | emb concat -> allE
  post1<<<1920, 256, 0, stream>>>(C, kParts, A, y1, A2f8, cnts1, tIdx1,
                                  tVal1, tvec, uemb, iemb, allE);
  // 5) A3 = A2*A (overwrite partials)
  gemm_f8<<<dim3(24, 24, kParts), 256, 0, stream>>>(A2f8, Atf8, C, kLen);
  // 6) post2: w0..w3 (single block)
  post2<<<1, 256, 0, stream>>>(vu, vv, y1, s1, tvec, wacc);
  // 7) build_light v3: 2-wave blocks, weight-folded lists, 8x-MLP gather
  build_light<<<NN, 128, 0, stream>>>(C, kParts, A, allE, uemb0, iemb0, wacc,
                                      cnts1, tIdx1, tVal1, lightOut);
  // 8) gather dots
  out_dot<<<BB / 4, 256, 0, stream>>>(users, items, lightOut, out);
}